// Round 4
// baseline (376.567 us; speedup 1.0000x reference)
//
#include <hip/hip_runtime.h>
#include <hip/hip_fp16.h>
#include <math.h>

// x [64,3,224,224] fp32; expert: conv3x3 s2 (3->64)+ReLU -> conv3x3 s2 (64->128)
// +ReLU -> GAP -> FC 128->2; blend on t softmax conf <= 0.9. Out: 129 floats.
// SAME s2: pad_lo=0, pad_hi=1 both convs.
//
// Round-9: conv2 waves fattened to M=64 (acc[4][7]); block = 2 M-halves x
// 2 row-pairs (4 out rows), grid x 28->14. Halves the B-fragment LDS
// redundancy (waves/M-split was re-reading every activation fragment 4x).
// Granule swizzle from round-7 reverted (it increased conflicts 7.2M->9.0M).
// conv1/prep unchanged (isolate the experiment).
//
// ws layout (bytes):
//   W2B_OFF: ushort(f16) w2frag[2 e][8 octile][18 kc][64 lane][8]
//            oc = octile*16 + (lane&15); kk = kc*32 + (lane>>4)*8 + j
//            kk = kh*192 + kw*64 + ic
//   W1F_OFF: ushort(f16) w1frag[2 e][4 m][64 lane][8]
//            oc = m*16 + (lane&15); kk = (lane>>4)*8 + j (k = ic*9+kh*3+kw, <27)
//   G_OFF:   float  g[2 e][64 b][128 oc]
//   H1_OFF:  ushort(f16) h1[2 e][64 b][113 row][113 hx][64 ic] (row/col 112 = 0)

#define W2B_OFF   0ull
#define W1F_OFF   294912ull
#define G_OFF     303104ull
#define H1_OFF    368640ull
#define H1E_US    52301824ull   // 64*113*113*64
#define H1B_US    817216ull     // 113*113*64
#define WS_NEED   (H1_OFF + 2ull*H1E_US*2ull + 4096ull)

typedef __attribute__((ext_vector_type(8))) short bf16x8;   // raw 16B chunk
typedef __attribute__((ext_vector_type(8))) _Float16 half8;
typedef __attribute__((ext_vector_type(4))) float f32x4;

__device__ inline ushort f2h(float v) {
  __half h = __float2half(v);            // v_cvt_f16_f32 (RNE)
  return *(ushort*)&h;
}

__global__ __launch_bounds__(256) void prep_new(
    const float* __restrict__ w2_t, const float* __restrict__ w2_f,
    const float* __restrict__ w1_t, const float* __restrict__ w1_f,
    char* __restrict__ ws) {
  int idx = blockIdx.x * 256 + threadIdx.x;
  ushort* w2frag = (ushort*)(ws + W2B_OFF);
  ushort* w1frag = (ushort*)(ws + W1F_OFF);
  if (idx < 147456) {
    int j    = idx & 7;
    int lane = (idx >> 3) & 63;
    int t2   = idx >> 9;          // [0,288)
    int kc   = t2 % 18;
    int t3   = t2 / 18;           // [0,16)
    int octile = t3 & 7;
    int e    = t3 >> 3;
    int oc = octile * 16 + (lane & 15);
    int kk = kc * 32 + (lane >> 4) * 8 + j;
    int kh = kk / 192, r2 = kk - kh * 192, kw = r2 >> 6, ic = r2 & 63;
    const float* src = e ? w2_f : w2_t;
    w2frag[idx] = f2h(src[((oc * 64 + ic) * 3 + kh) * 3 + kw]);
  } else if (idx < 147456 + 4096) {
    // w1frag: i2 = e*2048 + m*512 + lane*8 + j
    int i2   = idx - 147456;
    int j    = i2 & 7;
    int lane = (i2 >> 3) & 63;
    int m    = (i2 >> 9) & 3;
    int e    = (i2 >> 11) & 1;
    int oc = m * 16 + (lane & 15);
    int kk = (lane >> 4) * 8 + j;
    const float* src = e ? w1_f : w1_t;
    w1frag[i2] = f2h((kk < 27) ? src[oc * 27 + kk] : 0.f);
  }
}

// conv1 via MFMA. Block = (4-row group 0..27, b, e), 4 waves.
// Wave w: output row 4*gR+w, 7 N-tiles of 16 cols, 4 M-tiles (64 oc).
// x staged in LDS as zero-extended f16 u32; single-term f16 MFMA.
__global__ __launch_bounds__(256) void conv1_mfma(
    const float* __restrict__ x,
    const ushort* __restrict__ w1f_all,
    const float* __restrict__ b1_t, const float* __restrict__ b1_f,
    ushort* __restrict__ h1_all)
{
  const int gR  = blockIdx.x;   // output rows 4g..4g+3
  const int b   = blockIdx.y;
  const int e   = blockIdx.z;
  const int tid = threadIdx.x;
  const int w    = tid >> 6;
  const int lane = tid & 63;
  const int q    = lane >> 4;
  const int n    = lane & 15;

  ushort* h1b = h1_all + (size_t)e * H1E_US + (size_t)b * H1B_US;
  const float* b1 = e ? b1_f : b1_t;

  constexpr int CW = 233;                 // odd -> scrambles row banks
  __shared__ unsigned int xs[3 * 9 * CW]; // 25164 B: [ic][xr 0..8][col 0..224]

  // ---- stage x rows 8gR..8gR+8, cols 0..223 as f16 (zero-extended u32) ----
  const float* xb = x + (size_t)b * 150528;
  const int xr0 = 8 * gR;
  for (int i = tid; i < 1512; i += 256) {   // 3*9*56 float4 units
    int ic  = i / 504;
    int rem = i - ic * 504;
    int r   = rem / 56;
    int u   = rem - r * 56;
    int xr  = xr0 + r;
    float4 p = make_float4(0.f, 0.f, 0.f, 0.f);
    if (xr < 224) p = *(const float4*)(xb + (ic * 224 + xr) * 224 + 4 * u);
    int base = (ic * 9 + r) * CW + 4 * u;
    xs[base + 0] = (unsigned int)f2h(p.x);
    xs[base + 1] = (unsigned int)f2h(p.y);
    xs[base + 2] = (unsigned int)f2h(p.z);
    xs[base + 3] = (unsigned int)f2h(p.w);
  }
  if (tid < 27) xs[tid * CW + 224] = 0;   // SAME pad col 224

  // ---- zero pad column 112 of h1 (4 rows), and row 112 (block gR==0) ----
  h1b[((size_t)((4 * gR + (tid >> 6)) * 113 + 112)) * 64 + (tid & 63)] = 0;
  if (gR == 0) {
    unsigned int* z = (unsigned int*)&h1b[(size_t)112 * 113 * 64];
    for (int i = tid; i < 3616; i += 256) z[i] = 0;
  }

  // ---- per-lane weight fragments & bias ----
  half8 wf[4];
#pragma unroll
  for (int m = 0; m < 4; ++m)
    wf[m] = *(const half8*)&w1f_all[(((size_t)(e * 4 + m)) * 64 + lane) * 8];
  float4 bv[4];
#pragma unroll
  for (int m = 0; m < 4; ++m)
    bv[m] = *(const float4*)&b1[m * 16 + 4 * q];

  // ---- per-lane im2col gather offsets (k = q*8+j; k = ic*9+kh*3+kw) ----
  int off[8];
#pragma unroll
  for (int j = 0; j < 8; ++j) {
    int kk = q * 8 + j;
    if (kk < 27) {
      int ic = kk / 9;
      int r9 = kk - ic * 9;
      int kh = r9 / 3;
      int kw = r9 - kh * 3;
      off[j] = (ic * 9 + kh) * CW + kw;
    } else {
      off[j] = -1;
    }
  }

  __syncthreads();

  const int row   = 4 * gR + w;         // output row, always < 112
  const int rbase = (2 * w) * CW;       // local input row = 2w + kh

  for (int nt = 0; nt < 7; ++nt) {
    const int c = nt * 16 + n;          // output col, < 112
    const int base = rbase + 2 * c;
    unsigned int g[8];
#pragma unroll
    for (int j = 0; j < 8; ++j)
      g[j] = (off[j] >= 0) ? xs[base + off[j]] : 0u;
    union { half8 h; unsigned int u[4]; } bh;
#pragma unroll
    for (int p = 0; p < 4; ++p)
      bh.u[p] = (g[2 * p] & 0xffffu) | (g[2 * p + 1] << 16);
    f32x4 acc[4];
#pragma unroll
    for (int m = 0; m < 4; ++m) acc[m] = (f32x4){0.f, 0.f, 0.f, 0.f};
#pragma unroll
    for (int m = 0; m < 4; ++m)
      acc[m] = __builtin_amdgcn_mfma_f32_16x16x32_f16(wf[m], bh.h, acc[m], 0, 0, 0);
    // C/D: col=lane&15 (=px), row=4q+reg (oc within m-tile)
    size_t po = ((size_t)(row * 113 + c)) * 64 + 4 * q;
#pragma unroll
    for (int m = 0; m < 4; ++m) {
      ushort v0 = f2h(fmaxf(acc[m][0] + bv[m].x, 0.f));
      ushort v1 = f2h(fmaxf(acc[m][1] + bv[m].y, 0.f));
      ushort v2 = f2h(fmaxf(acc[m][2] + bv[m].z, 0.f));
      ushort v3 = f2h(fmaxf(acc[m][3] + bv[m].w, 0.f));
      uint2 uu;
      uu.x = (unsigned int)v0 | ((unsigned int)v1 << 16);
      uu.y = (unsigned int)v2 | ((unsigned int)v3 << 16);
      *(uint2*)&h1b[po + m * 16] = uu;
    }
  }
}

// conv2 via MFMA. Block (T=4-row group 0..13, b, e), 4 waves = 2 M x 2 N.
// Wave (wm, wn): octiles 4wm..4wm+3 (64 oc), out rows 4T+2wn+{0,1}, 112 px.
// Per kh: stage h1 rows 8T+kh+2s (s=0..3) into slot s; lane reads slot
// s = 2wn+rl. acc[4 m][7 nt].
__global__ __launch_bounds__(256) void conv2_mfma(
    const ushort* __restrict__ h1_all,
    const ushort* __restrict__ w2frag,
    const float* __restrict__ b2_t, const float* __restrict__ b2_f,
    float* __restrict__ g)
{
  const int T = blockIdx.x;
  const int b = blockIdx.y;
  const int e = blockIdx.z;
  const int tid  = threadIdx.x;
  const int w    = tid >> 6;
  const int wm   = w & 1;
  const int wn   = w >> 1;
  const int lane = tid & 63;
  const ushort* h1b = h1_all + (size_t)e * H1E_US + (size_t)b * H1B_US;
  const float* b2 = e ? b2_f : b2_t;

  __shared__ ushort hs[4 * 113 * 72];   // 63.6 KB

  const int q   = (lane >> 4) & 3;
  const int n   = lane & 15;
  const int pxl = lane & 7;
  const int rl  = (lane >> 3) & 1;
  const int s   = 2 * wn + rl;          // LDS slot this lane consumes

  f32x4 acc[4][7];
#pragma unroll
  for (int m = 0; m < 4; ++m)
#pragma unroll
    for (int nt = 0; nt < 7; ++nt) acc[m][nt] = (f32x4){0.f, 0.f, 0.f, 0.f};

  for (int kh = 0; kh < 3; ++kh) {
    __syncthreads();
    for (int i = tid; i < 3616; i += 256) {
      int ss  = i / 904;               // 0..3
      int rem = i - ss * 904;
      int hx = rem >> 3, gq = rem & 7;
      int R = 8 * T + kh + 2 * ss;     // <= 112 (row 112 = zero pad)
      *(bf16x8*)&hs[(ss * 113 + hx) * 72 + 8 * gq] =
          *(const bf16x8*)&h1b[((size_t)(R * 113 + hx)) * 64 + 8 * gq];
    }
    __syncthreads();
#pragma unroll
    for (int kw = 0; kw < 3; ++kw) {
#pragma unroll
      for (int icc = 0; icc < 2; ++icc) {
        const int kc = kh * 6 + kw * 2 + icc;
        half8 bf[7];
#pragma unroll
        for (int nt = 0; nt < 7; ++nt) {
          int hx = 2 * (8 * nt + pxl) + kw;
          bf[nt] = *(const half8*)&hs[(s * 113 + hx) * 72 + icc * 32 + 8 * q];
        }
#pragma unroll
        for (int m = 0; m < 4; ++m) {
          const int octile = 4 * wm + m;
          half8 af = *(const half8*)
              &w2frag[((size_t)((e * 8 + octile) * 18 + kc)) * 512 + lane * 8];
#pragma unroll
          for (int nt = 0; nt < 7; ++nt)
            acc[m][nt] = __builtin_amdgcn_mfma_f32_16x16x32_f16(
                af, bf[nt], acc[m][nt], 0, 0, 0);
        }
      }
    }
  }

#pragma unroll
  for (int m = 0; m < 4; ++m) {
#pragma unroll
    for (int reg = 0; reg < 4; ++reg) {
      const int oc = 64 * wm + 16 * m + 4 * q + reg;
      const float bias = b2[oc];
      float sacc = 0.f;
#pragma unroll
      for (int nt = 0; nt < 7; ++nt) sacc += fmaxf(acc[m][nt][reg] + bias, 0.f);
      sacc += __shfl_xor(sacc, 1);
      sacc += __shfl_xor(sacc, 2);
      sacc += __shfl_xor(sacc, 4);
      sacc += __shfl_xor(sacc, 8);
      if (n == 0) atomicAdd(&g[((size_t)e * 64 + b) * 128 + oc], sacc);
    }
  }
}

__global__ __launch_bounds__(64) void finale(
    const float* __restrict__ g,
    const float* __restrict__ t_wf, const float* __restrict__ t_bf,
    const float* __restrict__ f_wf, const float* __restrict__ f_bf,
    float* __restrict__ out)
{
  const int b = threadIdx.x;
  const float inv = 1.0f / 3136.0f;
  const float* gt = g + b * 128;
  const float* gf = g + (64 + b) * 128;
  float lt0 = t_bf[0], lt1 = t_bf[1];
  float lf0 = f_bf[0], lf1 = f_bf[1];
  for (int k = 0; k < 128; ++k) {
    float vt = gt[k] * inv;
    float vf = gf[k] * inv;
    lt0 = fmaf(vt, t_wf[2 * k],     lt0);
    lt1 = fmaf(vt, t_wf[2 * k + 1], lt1);
    lf0 = fmaf(vf, f_wf[2 * k],     lf0);
    lf1 = fmaf(vf, f_wf[2 * k + 1], lf1);
  }
  float m  = fmaxf(lt0, lt1);
  float e0 = expf(lt0 - m), e1 = expf(lt1 - m);
  float conf = fmaxf(e0, e1) / (e0 + e1);
  bool use2 = (conf <= 0.9f);
  out[2 * b]     = use2 ? 0.7f * lt0 + 0.3f * lf0 : lt0;
  out[2 * b + 1] = use2 ? 0.7f * lt1 + 0.3f * lf1 : lt1;
  unsigned long long mask = __ballot(use2);
  if (b == 0) out[128] = (float)__popcll(mask) * (1.0f / 64.0f);
}

// ---------------- fallback (ws too small): round-1 fused fp32 ----------------
__global__ __launch_bounds__(256) void transpose_w2(
    const float* __restrict__ w2_t, const float* __restrict__ w2_f,
    float* __restrict__ w2t) {
  int idx = blockIdx.x * 256 + threadIdx.x;
  int e = idx / 73728;
  int r = idx - e * 73728;
  int k = r >> 7, oc = r & 127;
  const float* src = e ? w2_f : w2_t;
  w2t[idx] = src[oc * 576 + k];
}

__global__ __launch_bounds__(256, 3) void fused_expert(
    const float* __restrict__ x,
    const float* __restrict__ w1_t, const float* __restrict__ b1_t,
    const float* __restrict__ b2_t,
    const float* __restrict__ w1_f, const float* __restrict__ b1_f,
    const float* __restrict__ b2_f,
    const float* __restrict__ w2t_all, float* __restrict__ g)
{
  const int tile = blockIdx.x, b = blockIdx.y, e = blockIdx.z;
  const int ty = tile >> 1, tx = tile & 1;
  const float* w1  = e ? w1_f : w1_t;
  const float* b1  = e ? b1_f : b1_t;
  const float* b2  = e ? b2_f : b2_t;
  const float* w2t = w2t_all + e * 73728;
  __shared__ float x_s[3 * 19 * 116];
  __shared__ float h1_s[8 * 9 * 58];
  __shared__ float w1_s[1728];
  const int tid = threadIdx.x;
  {
    const float* xb = x + (size_t)b * 150528;
    const int xr0 = ty * 16, xc0 = tx * 112;
    for (int idx = tid; idx < 3 * 19 * 116; idx += 256) {
      int ic = idx / (19 * 116);
      int rem = idx - ic * (19 * 116);
      int r = rem / 116, cc = rem - r * 116;
      int xr = xr0 + r, xc = xc0 + cc;
      float v = 0.f;
      if (xr < 224 && xc < 224 && cc < 115) v = xb[(ic * 224 + xr) * 224 + xc];
      x_s[idx] = v;
    }
    for (int idx = tid; idx < 1728; idx += 256) w1_s[idx] = w1[idx];
  }
  const int ocg = tid >> 4, posg = tid & 15;
  int pbase[7];
#pragma unroll
  for (int j = 0; j < 7; ++j) {
    int p = posg + 16 * j, py = p / 28, px = p - py * 28;
    pbase[j] = py * 2 * 58 + px * 2;
  }
  float acc[7][8];
#pragma unroll
  for (int j = 0; j < 7; ++j)
#pragma unroll
    for (int i = 0; i < 8; ++i) acc[j][i] = 0.f;
  const int hc_l = tid >> 5, l32 = tid & 31;
  for (int c = 0; c < 8; ++c) {
    __syncthreads();
    {
      const int hc = c * 8 + hc_l;
      const float bias = b1[hc];
      float wr[27];
#pragma unroll
      for (int qq = 0; qq < 27; ++qq) wr[qq] = w1_s[hc * 27 + qq];
      for (int p = l32; p < 513; p += 32) {
        int hy = p / 57, hx = p - hy * 57;
        float a = bias;
#pragma unroll
        for (int ic = 0; ic < 3; ++ic)
#pragma unroll
          for (int kh = 0; kh < 3; ++kh) {
            const float* row = &x_s[ic * (19 * 116) + (2 * hy + kh) * 116 + 2 * hx];
            a = fmaf(row[0], wr[ic * 9 + kh * 3 + 0], a);
            a = fmaf(row[1], wr[ic * 9 + kh * 3 + 1], a);
            a = fmaf(row[2], wr[ic * 9 + kh * 3 + 2], a);
          }
        float v = fmaxf(a, 0.f);
        int hy_g = ty * 8 + hy, hx_g = tx * 56 + hx;
        if (hy_g >= 112 || hx_g >= 112) v = 0.f;
        h1_s[hc_l * 522 + hy * 58 + hx] = v;
      }
    }
    __syncthreads();
    for (int ic_l = 0; ic_l < 8; ++ic_l) {
#pragma unroll
      for (int kh = 0; kh < 3; ++kh)
#pragma unroll
        for (int kw = 0; kw < 3; ++kw) {
          const int k = (c * 8 + ic_l) * 9 + kh * 3 + kw;
          const float4 wA = *(const float4*)(w2t + k * 128 + ocg * 8);
          const float4 wB = *(const float4*)(w2t + k * 128 + ocg * 8 + 4);
          const float* hp = &h1_s[ic_l * 522 + kh * 58 + kw];
#pragma unroll
          for (int j = 0; j < 7; ++j) {
            float h = hp[pbase[j]];
            acc[j][0] = fmaf(wA.x, h, acc[j][0]);
            acc[j][1] = fmaf(wA.y, h, acc[j][1]);
            acc[j][2] = fmaf(wA.z, h, acc[j][2]);
            acc[j][3] = fmaf(wA.w, h, acc[j][3]);
            acc[j][4] = fmaf(wB.x, h, acc[j][4]);
            acc[j][5] = fmaf(wB.y, h, acc[j][5]);
            acc[j][6] = fmaf(wB.z, h, acc[j][6]);
            acc[j][7] = fmaf(wB.w, h, acc[j][7]);
          }
        }
    }
  }
  __syncthreads();
  float* red = x_s;
#pragma unroll
  for (int i = 0; i < 8; ++i) {
    float bb = b2[ocg * 8 + i];
    float t = 0.f;
#pragma unroll
    for (int j = 0; j < 7; ++j) t += fmaxf(acc[j][i] + bb, 0.f);
    red[posg * 129 + ocg * 8 + i] = t;
  }
  __syncthreads();
  if (tid < 128) {
    float t = 0.f;
#pragma unroll
    for (int pg = 0; pg < 16; ++pg) t += red[pg * 129 + tid];
    atomicAdd(&g[(e * 64 + b) * 128 + tid], t);
  }
}

extern "C" void kernel_launch(void* const* d_in, const int* in_sizes, int n_in,
                              void* d_out, int out_size, void* d_ws, size_t ws_size,
                              hipStream_t stream) {
  const float* x    = (const float*)d_in[0];
  const float* t_w1 = (const float*)d_in[1];
  const float* t_b1 = (const float*)d_in[2];
  const float* t_w2 = (const float*)d_in[3];
  const float* t_b2 = (const float*)d_in[4];
  const float* t_wf = (const float*)d_in[5];
  const float* t_bf = (const float*)d_in[6];
  const float* f_w1 = (const float*)d_in[7];
  const float* f_b1 = (const float*)d_in[8];
  const float* f_w2 = (const float*)d_in[9];
  const float* f_b2 = (const float*)d_in[10];
  const float* f_wf = (const float*)d_in[11];
  const float* f_bf = (const float*)d_in[12];
  float* out = (float*)d_out;
  char* ws = (char*)d_ws;

  if (ws_size >= WS_NEED) {
    float*  gbuf   = (float*)(ws + G_OFF);
    ushort* h1     = (ushort*)(ws + H1_OFF);
    ushort* w2frag = (ushort*)(ws + W2B_OFF);
    ushort* w1f    = (ushort*)(ws + W1F_OFF);
    hipMemsetAsync(gbuf, 0, 2 * 64 * 128 * sizeof(float), stream);
    prep_new<<<592, 256, 0, stream>>>(t_w2, f_w2, t_w1, f_w1, ws);
    conv1_mfma<<<dim3(28, 64, 2), 256, 0, stream>>>(x, w1f, t_b1, f_b1, h1);
    conv2_mfma<<<dim3(14, 64, 2), 256, 0, stream>>>(h1, w2frag, t_b2, f_b2, gbuf);
    finale<<<1, 64, 0, stream>>>(gbuf, t_wf, t_bf, f_wf, f_bf, out);
  } else {
    float* w2t = (float*)ws;
    float* g2  = (float*)(ws + 589824);
    hipMemsetAsync(g2, 0, 2 * 64 * 128 * sizeof(float), stream);
    transpose_w2<<<576, 256, 0, stream>>>(t_w2, f_w2, w2t);
    fused_expert<<<dim3(28, 64, 2), 256, 0, stream>>>(
        x, t_w1, t_b1, t_b2, f_w1, f_b1, f_b2, w2t, g2);
    finale<<<1, 64, 0, stream>>>(g2, t_wf, t_bf, f_wf, f_bf, out);
  }
}

// Round 5
// 245.361 us; speedup vs baseline: 1.5347x; 1.5347x over previous
//
#include <hip/hip_runtime.h>
#include <hip/hip_fp16.h>
#include <math.h>

// x [64,3,224,224] fp32; expert: conv3x3 s2 (3->64)+ReLU -> conv3x3 s2 (64->128)
// +ReLU -> GAP -> FC 128->2; blend on t softmax conf <= 0.9. Out: 129 floats.
// SAME s2: pad_lo=0, pad_hi=1 both convs. conv2 output is 56x56 (GAP/3136).
//
// Round-10:
//  * conv2 reverted to round-3 geometry (M=32/wave, 2 out rows/block) but
//    restructured: stage the block's 5 h1 rows ONCE (72.3KB LDS), ONE barrier,
//    then the whole 252-MFMA compute runs with no further syncs (round-3/4 had
//    6 vmcnt(0)+barrier drains/block -> latency soup, all pipes <25%).
//    LDS granule XOR swizzle g^=(hx&7): bank = 4*(g^..) since row stride
//    128B == 0 mod 8 granules; gives exactly 8 lanes per 4-bank group = wave64
//    minimum (conflict-free). Round-7's (hx>>1)&7 swizzle was wrong axis.
//  * conv1 h1 stores made fully coalesced: store oc m*16+4q+reg at channel
//    slot q*16+m*4+reg -> per lane 32B contiguous (2x dwordx4), per wave 2KB
//    dense (was 16 scattered 32B segments per store inst; h1 = 209MB written).
//    The channel permutation is baked into w2frag in prep (icp below).
//
// ws layout (bytes):
//   W2B_OFF: ushort(f16) w2frag[2 e][8 octile][18 kc][64 lane][8]
//            oc = octile*16 + (lane&15); kk = kc*32 + (lane>>4)*8 + j
//            kk = kh*192 + kw*64 + slot; w2 source ic = perm(slot)
//   W1F_OFF: ushort(f16) w1frag[2 e][4 m][64 lane][8]
//            oc = m*16 + (lane&15); kk = (lane>>4)*8 + j (k = ic*9+kh*3+kw, <27)
//   G_OFF:   float  g[2 e][64 b][128 oc]
//   H1_OFF:  ushort(f16) h1[2 e][64 b][113 row][113 hx][64 slot] (row/col 112=0)

#define W2B_OFF   0ull
#define W1F_OFF   294912ull
#define G_OFF     303104ull
#define H1_OFF    368640ull
#define H1E_US    52301824ull   // 64*113*113*64
#define H1B_US    817216ull     // 113*113*64
#define WS_NEED   (H1_OFF + 2ull*H1E_US*2ull + 4096ull)

typedef __attribute__((ext_vector_type(8))) short bf16x8;   // raw 16B chunk
typedef __attribute__((ext_vector_type(8))) _Float16 half8;
typedef __attribute__((ext_vector_type(4))) float f32x4;

__device__ inline ushort f2h(float v) {
  __half h = __float2half(v);            // v_cvt_f16_f32 (RNE)
  return *(ushort*)&h;
}

__global__ __launch_bounds__(256) void prep_new(
    const float* __restrict__ w2_t, const float* __restrict__ w2_f,
    const float* __restrict__ w1_t, const float* __restrict__ w1_f,
    char* __restrict__ ws) {
  int idx = blockIdx.x * 256 + threadIdx.x;
  ushort* w2frag = (ushort*)(ws + W2B_OFF);
  ushort* w1frag = (ushort*)(ws + W1F_OFF);
  if (idx < 147456) {
    int j    = idx & 7;
    int lane = (idx >> 3) & 63;
    int t2   = idx >> 9;          // [0,288)
    int kc   = t2 % 18;
    int t3   = t2 / 18;           // [0,16)
    int octile = t3 & 7;
    int e    = t3 >> 3;
    int oc = octile * 16 + (lane & 15);
    int kk = kc * 32 + (lane >> 4) * 8 + j;
    int kh = kk / 192, r2 = kk - kh * 192, kw = r2 >> 6, slot = r2 & 63;
    // conv1 stores oc m*16+4q+reg at h1 slot q*16+m*4+reg -> invert here:
    int icp = ((slot >> 2) & 3) * 16 + ((slot >> 4) & 3) * 4 + (slot & 3);
    const float* src = e ? w2_f : w2_t;
    w2frag[idx] = f2h(src[((oc * 64 + icp) * 3 + kh) * 3 + kw]);
  } else if (idx < 147456 + 4096) {
    // w1frag: i2 = e*2048 + m*512 + lane*8 + j
    int i2   = idx - 147456;
    int j    = i2 & 7;
    int lane = (i2 >> 3) & 63;
    int m    = (i2 >> 9) & 3;
    int e    = (i2 >> 11) & 1;
    int oc = m * 16 + (lane & 15);
    int kk = (lane >> 4) * 8 + j;
    const float* src = e ? w1_f : w1_t;
    w1frag[i2] = f2h((kk < 27) ? src[oc * 27 + kk] : 0.f);
  }
}

// conv1 via MFMA. Block = (4-row group 0..27, b, e), 4 waves.
// Wave w: output row 4*gR+w, 7 N-tiles of 16 cols, 4 M-tiles (64 oc).
// x staged in LDS as zero-extended f16 u32; single-term f16 MFMA.
// h1 channel slot = q*16+m*4+reg (coalesced 32B/lane stores).
__global__ __launch_bounds__(256) void conv1_mfma(
    const float* __restrict__ x,
    const ushort* __restrict__ w1f_all,
    const float* __restrict__ b1_t, const float* __restrict__ b1_f,
    ushort* __restrict__ h1_all)
{
  const int gR  = blockIdx.x;   // output rows 4g..4g+3
  const int b   = blockIdx.y;
  const int e   = blockIdx.z;
  const int tid = threadIdx.x;
  const int w    = tid >> 6;
  const int lane = tid & 63;
  const int q    = lane >> 4;
  const int n    = lane & 15;

  ushort* h1b = h1_all + (size_t)e * H1E_US + (size_t)b * H1B_US;
  const float* b1 = e ? b1_f : b1_t;

  constexpr int CW = 233;                 // odd -> scrambles row banks
  __shared__ unsigned int xs[3 * 9 * CW]; // 25164 B: [ic][xr 0..8][col 0..224]

  // ---- stage x rows 8gR..8gR+8, cols 0..223 as f16 (zero-extended u32) ----
  const float* xb = x + (size_t)b * 150528;
  const int xr0 = 8 * gR;
  for (int i = tid; i < 1512; i += 256) {   // 3*9*56 float4 units
    int ic  = i / 504;
    int rem = i - ic * 504;
    int r   = rem / 56;
    int u   = rem - r * 56;
    int xr  = xr0 + r;
    float4 p = make_float4(0.f, 0.f, 0.f, 0.f);
    if (xr < 224) p = *(const float4*)(xb + (ic * 224 + xr) * 224 + 4 * u);
    int base = (ic * 9 + r) * CW + 4 * u;
    xs[base + 0] = (unsigned int)f2h(p.x);
    xs[base + 1] = (unsigned int)f2h(p.y);
    xs[base + 2] = (unsigned int)f2h(p.z);
    xs[base + 3] = (unsigned int)f2h(p.w);
  }
  if (tid < 27) xs[tid * CW + 224] = 0;   // SAME pad col 224

  // ---- zero pad column 112 of h1 (4 rows), and row 112 (block gR==0) ----
  h1b[((size_t)((4 * gR + (tid >> 6)) * 113 + 112)) * 64 + (tid & 63)] = 0;
  if (gR == 0) {
    unsigned int* z = (unsigned int*)&h1b[(size_t)112 * 113 * 64];
    for (int i = tid; i < 3616; i += 256) z[i] = 0;
  }

  // ---- per-lane weight fragments & bias ----
  half8 wf[4];
#pragma unroll
  for (int m = 0; m < 4; ++m)
    wf[m] = *(const half8*)&w1f_all[(((size_t)(e * 4 + m)) * 64 + lane) * 8];
  float4 bv[4];
#pragma unroll
  for (int m = 0; m < 4; ++m)
    bv[m] = *(const float4*)&b1[m * 16 + 4 * q];

  // ---- per-lane im2col gather offsets (k = q*8+j; k = ic*9+kh*3+kw) ----
  int off[8];
#pragma unroll
  for (int j = 0; j < 8; ++j) {
    int kk = q * 8 + j;
    if (kk < 27) {
      int ic = kk / 9;
      int r9 = kk - ic * 9;
      int kh = r9 / 3;
      int kw = r9 - kh * 3;
      off[j] = (ic * 9 + kh) * CW + kw;
    } else {
      off[j] = -1;
    }
  }

  __syncthreads();

  const int row   = 4 * gR + w;         // output row, always < 112
  const int rbase = (2 * w) * CW;       // local input row = 2w + kh

  for (int nt = 0; nt < 7; ++nt) {
    const int c = nt * 16 + n;          // output col, < 112
    const int base = rbase + 2 * c;
    unsigned int g[8];
#pragma unroll
    for (int j = 0; j < 8; ++j)
      g[j] = (off[j] >= 0) ? xs[base + off[j]] : 0u;
    union { half8 h; unsigned int u[4]; } bh;
#pragma unroll
    for (int p = 0; p < 4; ++p)
      bh.u[p] = (g[2 * p] & 0xffffu) | (g[2 * p + 1] << 16);
    f32x4 acc[4];
#pragma unroll
    for (int m = 0; m < 4; ++m) acc[m] = (f32x4){0.f, 0.f, 0.f, 0.f};
#pragma unroll
    for (int m = 0; m < 4; ++m)
      acc[m] = __builtin_amdgcn_mfma_f32_16x16x32_f16(wf[m], bh.h, acc[m], 0, 0, 0);
    // C/D: col=lane&15 (=px), row=4q+reg (oc = m*16+4q+reg)
    // store slot = q*16 + m*4 + reg  -> lane covers 32B contiguous
    size_t po = ((size_t)(row * 113 + c)) * 64 + q * 16;
    union { ushort us[16]; uint4 v4[2]; } pk;
#pragma unroll
    for (int m = 0; m < 4; ++m) {
      pk.us[m * 4 + 0] = f2h(fmaxf(acc[m][0] + bv[m].x, 0.f));
      pk.us[m * 4 + 1] = f2h(fmaxf(acc[m][1] + bv[m].y, 0.f));
      pk.us[m * 4 + 2] = f2h(fmaxf(acc[m][2] + bv[m].z, 0.f));
      pk.us[m * 4 + 3] = f2h(fmaxf(acc[m][3] + bv[m].w, 0.f));
    }
    *(uint4*)&h1b[po]     = pk.v4[0];
    *(uint4*)&h1b[po + 8] = pk.v4[1];
  }
}

// conv2 via MFMA. Block (T 0..27, b, e), 4 waves. Out rows {2T, 2T+1} (56 rows).
// Wave w: octiles {2w,2w+1} (32 oc), 7 N-tiles (8px x 2rows), all 18 kc.
// Stage-once: h1 rows 4T..4T+4 in LDS (5x113x64 ushort = 72.3KB), ONE barrier,
// then barrier-free compute. Granule swizzle: granule g of col hx stored at
// g^(hx&7) -> reads conflict-free (8 lanes per 4-bank group).
__global__ __launch_bounds__(256) void conv2_mfma(
    const ushort* __restrict__ h1_all,
    const ushort* __restrict__ w2frag,
    const float* __restrict__ b2_t, const float* __restrict__ b2_f,
    float* __restrict__ g)
{
  const int T = blockIdx.x;
  const int b = blockIdx.y;
  const int e = blockIdx.z;
  const int tid  = threadIdx.x;
  const int w    = tid >> 6;
  const int lane = tid & 63;
  const ushort* h1b = h1_all + (size_t)e * H1E_US + (size_t)b * H1B_US;
  const float* b2 = e ? b2_f : b2_t;

  __shared__ ushort hs[5 * 113 * 64];   // 72320 B

  const int q   = lane >> 4;
  const int n   = lane & 15;
  const int pxl = lane & 7;
  const int rl  = (lane >> 3) & 1;

  // ---- stage 5 h1 rows (4520 granules of 16B), swizzled, reg-staged ----
#pragma unroll
  for (int half = 0; half < 2; ++half) {
    bf16x8 tmp[9];
    int dst[9];
    bool ok[9];
#pragma unroll
    for (int k = 0; k < 9; ++k) {
      int s = tid + (half * 9 + k) * 256;
      ok[k] = (s < 4520);
      int r = s / 904;
      int rem = s - 904 * r;
      int hx = rem >> 3, gq = rem & 7;
      if (ok[k])
        tmp[k] = *(const bf16x8*)&h1b[((size_t)((4 * T + r) * 113 + hx)) * 64 + 8 * gq];
      dst[k] = (r * 113 + hx) * 64 + 8 * (gq ^ (hx & 7));
    }
#pragma unroll
    for (int k = 0; k < 9; ++k)
      if (ok[k]) *(bf16x8*)&hs[dst[k]] = tmp[k];
  }
  __syncthreads();

  f32x4 acc[2][7];
#pragma unroll
  for (int mt = 0; mt < 2; ++mt)
#pragma unroll
    for (int nt = 0; nt < 7; ++nt) acc[mt][nt] = (f32x4){0.f, 0.f, 0.f, 0.f};

  for (int kh = 0; kh < 3; ++kh) {
    const int rbase = (kh + 2 * rl) * 113 * 64;   // local h1 row = kh+2*rl
#pragma unroll
    for (int kw = 0; kw < 3; ++kw) {
#pragma unroll
      for (int icc = 0; icc < 2; ++icc) {
        const int kc = kh * 6 + kw * 2 + icc;
        const int gsw = 8 * ((icc * 4 + q) ^ ((2 * pxl + kw) & 7));
        half8 bf[7];
#pragma unroll
        for (int nt = 0; nt < 7; ++nt) {
          int hx = 2 * (8 * nt + pxl) + kw;
          bf[nt] = *(const half8*)&hs[rbase + hx * 64 + gsw];
        }
#pragma unroll
        for (int mt = 0; mt < 2; ++mt) {
          const int octile = 2 * w + mt;
          half8 af = *(const half8*)
              &w2frag[((size_t)((e * 8 + octile) * 18 + kc)) * 512 + lane * 8];
#pragma unroll
          for (int nt = 0; nt < 7; ++nt)
            acc[mt][nt] = __builtin_amdgcn_mfma_f32_16x16x32_f16(
                af, bf[nt], acc[mt][nt], 0, 0, 0);
        }
      }
    }
  }

#pragma unroll
  for (int mt = 0; mt < 2; ++mt) {
#pragma unroll
    for (int reg = 0; reg < 4; ++reg) {
      const int oc = 32 * w + 16 * mt + 4 * q + reg;
      const float bias = b2[oc];
      float s = 0.f;
#pragma unroll
      for (int nt = 0; nt < 7; ++nt) s += fmaxf(acc[mt][nt][reg] + bias, 0.f);
      s += __shfl_xor(s, 1);
      s += __shfl_xor(s, 2);
      s += __shfl_xor(s, 4);
      s += __shfl_xor(s, 8);
      if (n == 0) atomicAdd(&g[((size_t)e * 64 + b) * 128 + oc], s);
    }
  }
}

__global__ __launch_bounds__(64) void finale(
    const float* __restrict__ g,
    const float* __restrict__ t_wf, const float* __restrict__ t_bf,
    const float* __restrict__ f_wf, const float* __restrict__ f_bf,
    float* __restrict__ out)
{
  const int b = threadIdx.x;
  const float inv = 1.0f / 3136.0f;
  const float* gt = g + b * 128;
  const float* gf = g + (64 + b) * 128;
  float lt0 = t_bf[0], lt1 = t_bf[1];
  float lf0 = f_bf[0], lf1 = f_bf[1];
  for (int k = 0; k < 128; ++k) {
    float vt = gt[k] * inv;
    float vf = gf[k] * inv;
    lt0 = fmaf(vt, t_wf[2 * k],     lt0);
    lt1 = fmaf(vt, t_wf[2 * k + 1], lt1);
    lf0 = fmaf(vf, f_wf[2 * k],     lf0);
    lf1 = fmaf(vf, f_wf[2 * k + 1], lf1);
  }
  float m  = fmaxf(lt0, lt1);
  float e0 = expf(lt0 - m), e1 = expf(lt1 - m);
  float conf = fmaxf(e0, e1) / (e0 + e1);
  bool use2 = (conf <= 0.9f);
  out[2 * b]     = use2 ? 0.7f * lt0 + 0.3f * lf0 : lt0;
  out[2 * b + 1] = use2 ? 0.7f * lt1 + 0.3f * lf1 : lt1;
  unsigned long long mask = __ballot(use2);
  if (b == 0) out[128] = (float)__popcll(mask) * (1.0f / 64.0f);
}

// ---------------- fallback (ws too small): round-1 fused fp32 ----------------
__global__ __launch_bounds__(256) void transpose_w2(
    const float* __restrict__ w2_t, const float* __restrict__ w2_f,
    float* __restrict__ w2t) {
  int idx = blockIdx.x * 256 + threadIdx.x;
  int e = idx / 73728;
  int r = idx - e * 73728;
  int k = r >> 7, oc = r & 127;
  const float* src = e ? w2_f : w2_t;
  w2t[idx] = src[oc * 576 + k];
}

__global__ __launch_bounds__(256, 3) void fused_expert(
    const float* __restrict__ x,
    const float* __restrict__ w1_t, const float* __restrict__ b1_t,
    const float* __restrict__ b2_t,
    const float* __restrict__ w1_f, const float* __restrict__ b1_f,
    const float* __restrict__ b2_f,
    const float* __restrict__ w2t_all, float* __restrict__ g)
{
  const int tile = blockIdx.x, b = blockIdx.y, e = blockIdx.z;
  const int ty = tile >> 1, tx = tile & 1;
  const float* w1  = e ? w1_f : w1_t;
  const float* b1  = e ? b1_f : b1_t;
  const float* b2  = e ? b2_f : b2_t;
  const float* w2t = w2t_all + e * 73728;
  __shared__ float x_s[3 * 19 * 116];
  __shared__ float h1_s[8 * 9 * 58];
  __shared__ float w1_s[1728];
  const int tid = threadIdx.x;
  {
    const float* xb = x + (size_t)b * 150528;
    const int xr0 = ty * 16, xc0 = tx * 112;
    for (int idx = tid; idx < 3 * 19 * 116; idx += 256) {
      int ic = idx / (19 * 116);
      int rem = idx - ic * (19 * 116);
      int r = rem / 116, cc = rem - r * 116;
      int xr = xr0 + r, xc = xc0 + cc;
      float v = 0.f;
      if (xr < 224 && xc < 224 && cc < 115) v = xb[(ic * 224 + xr) * 224 + xc];
      x_s[idx] = v;
    }
    for (int idx = tid; idx < 1728; idx += 256) w1_s[idx] = w1[idx];
  }
  const int ocg = tid >> 4, posg = tid & 15;
  int pbase[7];
#pragma unroll
  for (int j = 0; j < 7; ++j) {
    int p = posg + 16 * j, py = p / 28, px = p - py * 28;
    pbase[j] = py * 2 * 58 + px * 2;
  }
  float acc[7][8];
#pragma unroll
  for (int j = 0; j < 7; ++j)
#pragma unroll
    for (int i = 0; i < 8; ++i) acc[j][i] = 0.f;
  const int hc_l = tid >> 5, l32 = tid & 31;
  for (int c = 0; c < 8; ++c) {
    __syncthreads();
    {
      const int hc = c * 8 + hc_l;
      const float bias = b1[hc];
      float wr[27];
#pragma unroll
      for (int qq = 0; qq < 27; ++qq) wr[qq] = w1_s[hc * 27 + qq];
      for (int p = l32; p < 513; p += 32) {
        int hy = p / 57, hx = p - hy * 57;
        float a = bias;
#pragma unroll
        for (int ic = 0; ic < 3; ++ic)
#pragma unroll
          for (int kh = 0; kh < 3; ++kh) {
            const float* row = &x_s[ic * (19 * 116) + (2 * hy + kh) * 116 + 2 * hx];
            a = fmaf(row[0], wr[ic * 9 + kh * 3 + 0], a);
            a = fmaf(row[1], wr[ic * 9 + kh * 3 + 1], a);
            a = fmaf(row[2], wr[ic * 9 + kh * 3 + 2], a);
          }
        float v = fmaxf(a, 0.f);
        int hy_g = ty * 8 + hy, hx_g = tx * 56 + hx;
        if (hy_g >= 112 || hx_g >= 112) v = 0.f;
        h1_s[hc_l * 522 + hy * 58 + hx] = v;
      }
    }
    __syncthreads();
    for (int ic_l = 0; ic_l < 8; ++ic_l) {
#pragma unroll
      for (int kh = 0; kh < 3; ++kh)
#pragma unroll
        for (int kw = 0; kw < 3; ++kw) {
          const int k = (c * 8 + ic_l) * 9 + kh * 3 + kw;
          const float4 wA = *(const float4*)(w2t + k * 128 + ocg * 8);
          const float4 wB = *(const float4*)(w2t + k * 128 + ocg * 8 + 4);
          const float* hp = &h1_s[ic_l * 522 + kh * 58 + kw];
#pragma unroll
          for (int j = 0; j < 7; ++j) {
            float h = hp[pbase[j]];
            acc[j][0] = fmaf(wA.x, h, acc[j][0]);
            acc[j][1] = fmaf(wA.y, h, acc[j][1]);
            acc[j][2] = fmaf(wA.z, h, acc[j][2]);
            acc[j][3] = fmaf(wA.w, h, acc[j][3]);
            acc[j][4] = fmaf(wB.x, h, acc[j][4]);
            acc[j][5] = fmaf(wB.y, h, acc[j][5]);
            acc[j][6] = fmaf(wB.z, h, acc[j][6]);
            acc[j][7] = fmaf(wB.w, h, acc[j][7]);
          }
        }
    }
  }
  __syncthreads();
  float* red = x_s;
#pragma unroll
  for (int i = 0; i < 8; ++i) {
    float bb = b2[ocg * 8 + i];
    float t = 0.f;
#pragma unroll
    for (int j = 0; j < 7; ++j) t += fmaxf(acc[j][i] + bb, 0.f);
    red[posg * 129 + ocg * 8 + i] = t;
  }
  __syncthreads();
  if (tid < 128) {
    float t = 0.f;
#pragma unroll
    for (int pg = 0; pg < 16; ++pg) t += red[pg * 129 + tid];
    atomicAdd(&g[(e * 64 + b) * 128 + tid], t);
  }
}

extern "C" void kernel_launch(void* const* d_in, const int* in_sizes, int n_in,
                              void* d_out, int out_size, void* d_ws, size_t ws_size,
                              hipStream_t stream) {
  const float* x    = (const float*)d_in[0];
  const float* t_w1 = (const float*)d_in[1];
  const float* t_b1 = (const float*)d_in[2];
  const float* t_w2 = (const float*)d_in[3];
  const float* t_b2 = (const float*)d_in[4];
  const float* t_wf = (const float*)d_in[5];
  const float* t_bf = (const float*)d_in[6];
  const float* f_w1 = (const float*)d_in[7];
  const float* f_b1 = (const float*)d_in[8];
  const float* f_w2 = (const float*)d_in[9];
  const float* f_b2 = (const float*)d_in[10];
  const float* f_wf = (const float*)d_in[11];
  const float* f_bf = (const float*)d_in[12];
  float* out = (float*)d_out;
  char* ws = (char*)d_ws;

  if (ws_size >= WS_NEED) {
    float*  gbuf   = (float*)(ws + G_OFF);
    ushort* h1     = (ushort*)(ws + H1_OFF);
    ushort* w2frag = (ushort*)(ws + W2B_OFF);
    ushort* w1f    = (ushort*)(ws + W1F_OFF);
    hipMemsetAsync(gbuf, 0, 2 * 64 * 128 * sizeof(float), stream);
    prep_new<<<592, 256, 0, stream>>>(t_w2, f_w2, t_w1, f_w1, ws);
    conv1_mfma<<<dim3(28, 64, 2), 256, 0, stream>>>(x, w1f, t_b1, f_b1, h1);
    conv2_mfma<<<dim3(28, 64, 2), 256, 0, stream>>>(h1, w2frag, t_b2, f_b2, gbuf);
    finale<<<1, 64, 0, stream>>>(gbuf, t_wf, t_bf, f_wf, f_bf, out);
  } else {
    float* w2t = (float*)ws;
    float* g2  = (float*)(ws + 589824);
    hipMemsetAsync(g2, 0, 2 * 64 * 128 * sizeof(float), stream);
    transpose_w2<<<576, 256, 0, stream>>>(t_w2, f_w2, w2t);
    fused_expert<<<dim3(28, 64, 2), 256, 0, stream>>>(
        x, t_w1, t_b1, t_b2, f_w1, f_b1, f_b2, w2t, g2);
    finale<<<1, 64, 0, stream>>>(g2, t_wf, t_bf, f_wf, f_bf, out);
  }
}

// Round 6
// 239.614 us; speedup vs baseline: 1.5716x; 1.0240x over previous
//
#include <hip/hip_runtime.h>
#include <hip/hip_fp16.h>
#include <math.h>

// x [64,3,224,224] fp32; expert: conv3x3 s2 (3->64)+ReLU -> conv3x3 s2 (64->128)
// +ReLU -> GAP -> FC 128->2; blend on t softmax conf <= 0.9. Out: 129 floats.
// SAME s2: pad_lo=0, pad_hi=1 both convs. conv2 output is 56x56 (GAP/3136).
//
// Round-11: conv2 af (w2 weight fragments) fully preloaded to registers
// (2 mt x 18 kc x 16B = 144 VGPR, issued BEFORE h1 staging so L2 latency
// hides under the stage+barrier; kh loop fully unrolled so all af indices
// are compile-time). Inner loop is now pure ds_read_b128 + MFMA -> removes
// the ~200cyc/kc exposed L2 latency that held all pipes at ~25%.
// __launch_bounds__(256,2): occupancy is LDS-capped (72.7KB -> 2 blocks/CU),
// so up to 256 VGPR is free.
// Note: SQ_LDS_BANK_CONFLICT ~7.2M is a structural b128 artifact
// (4/instruction), NOT real conflicts — reads are conflict-free since r10.
//
// ws layout (bytes):
//   W2B_OFF: ushort(f16) w2frag[2 e][8 octile][18 kc][64 lane][8]
//            oc = octile*16 + (lane&15); kk = kc*32 + (lane>>4)*8 + j
//            kk = kh*192 + kw*64 + slot; w2 source ic = perm(slot)
//   W1F_OFF: ushort(f16) w1frag[2 e][4 m][64 lane][8]
//            oc = m*16 + (lane&15); kk = (lane>>4)*8 + j (k = ic*9+kh*3+kw, <27)
//   G_OFF:   float  g[2 e][64 b][128 oc]
//   H1_OFF:  ushort(f16) h1[2 e][64 b][113 row][113 hx][64 slot] (row/col 112=0)

#define W2B_OFF   0ull
#define W1F_OFF   294912ull
#define G_OFF     303104ull
#define H1_OFF    368640ull
#define H1E_US    52301824ull   // 64*113*113*64
#define H1B_US    817216ull     // 113*113*64
#define WS_NEED   (H1_OFF + 2ull*H1E_US*2ull + 4096ull)

typedef __attribute__((ext_vector_type(8))) short bf16x8;   // raw 16B chunk
typedef __attribute__((ext_vector_type(8))) _Float16 half8;
typedef __attribute__((ext_vector_type(4))) float f32x4;

__device__ inline ushort f2h(float v) {
  __half h = __float2half(v);            // v_cvt_f16_f32 (RNE)
  return *(ushort*)&h;
}

__global__ __launch_bounds__(256) void prep_new(
    const float* __restrict__ w2_t, const float* __restrict__ w2_f,
    const float* __restrict__ w1_t, const float* __restrict__ w1_f,
    char* __restrict__ ws) {
  int idx = blockIdx.x * 256 + threadIdx.x;
  ushort* w2frag = (ushort*)(ws + W2B_OFF);
  ushort* w1frag = (ushort*)(ws + W1F_OFF);
  if (idx < 147456) {
    int j    = idx & 7;
    int lane = (idx >> 3) & 63;
    int t2   = idx >> 9;          // [0,288)
    int kc   = t2 % 18;
    int t3   = t2 / 18;           // [0,16)
    int octile = t3 & 7;
    int e    = t3 >> 3;
    int oc = octile * 16 + (lane & 15);
    int kk = kc * 32 + (lane >> 4) * 8 + j;
    int kh = kk / 192, r2 = kk - kh * 192, kw = r2 >> 6, slot = r2 & 63;
    // conv1 stores oc m*16+4q+reg at h1 slot q*16+m*4+reg -> invert here:
    int icp = ((slot >> 2) & 3) * 16 + ((slot >> 4) & 3) * 4 + (slot & 3);
    const float* src = e ? w2_f : w2_t;
    w2frag[idx] = f2h(src[((oc * 64 + icp) * 3 + kh) * 3 + kw]);
  } else if (idx < 147456 + 4096) {
    // w1frag: i2 = e*2048 + m*512 + lane*8 + j
    int i2   = idx - 147456;
    int j    = i2 & 7;
    int lane = (i2 >> 3) & 63;
    int m    = (i2 >> 9) & 3;
    int e    = (i2 >> 11) & 1;
    int oc = m * 16 + (lane & 15);
    int kk = (lane >> 4) * 8 + j;
    const float* src = e ? w1_f : w1_t;
    w1frag[i2] = f2h((kk < 27) ? src[oc * 27 + kk] : 0.f);
  }
}

// conv1 via MFMA. Block = (4-row group 0..27, b, e), 4 waves.
// Wave w: output row 4*gR+w, 7 N-tiles of 16 cols, 4 M-tiles (64 oc).
// x staged in LDS as zero-extended f16 u32; single-term f16 MFMA.
// h1 channel slot = q*16+m*4+reg (coalesced 32B/lane stores).
__global__ __launch_bounds__(256) void conv1_mfma(
    const float* __restrict__ x,
    const ushort* __restrict__ w1f_all,
    const float* __restrict__ b1_t, const float* __restrict__ b1_f,
    ushort* __restrict__ h1_all)
{
  const int gR  = blockIdx.x;   // output rows 4g..4g+3
  const int b   = blockIdx.y;
  const int e   = blockIdx.z;
  const int tid = threadIdx.x;
  const int w    = tid >> 6;
  const int lane = tid & 63;
  const int q    = lane >> 4;
  const int n    = lane & 15;

  ushort* h1b = h1_all + (size_t)e * H1E_US + (size_t)b * H1B_US;
  const float* b1 = e ? b1_f : b1_t;

  constexpr int CW = 233;                 // odd -> scrambles row banks
  __shared__ unsigned int xs[3 * 9 * CW]; // 25164 B: [ic][xr 0..8][col 0..224]

  // ---- stage x rows 8gR..8gR+8, cols 0..223 as f16 (zero-extended u32) ----
  const float* xb = x + (size_t)b * 150528;
  const int xr0 = 8 * gR;
  for (int i = tid; i < 1512; i += 256) {   // 3*9*56 float4 units
    int ic  = i / 504;
    int rem = i - ic * 504;
    int r   = rem / 56;
    int u   = rem - r * 56;
    int xr  = xr0 + r;
    float4 p = make_float4(0.f, 0.f, 0.f, 0.f);
    if (xr < 224) p = *(const float4*)(xb + (ic * 224 + xr) * 224 + 4 * u);
    int base = (ic * 9 + r) * CW + 4 * u;
    xs[base + 0] = (unsigned int)f2h(p.x);
    xs[base + 1] = (unsigned int)f2h(p.y);
    xs[base + 2] = (unsigned int)f2h(p.z);
    xs[base + 3] = (unsigned int)f2h(p.w);
  }
  if (tid < 27) xs[tid * CW + 224] = 0;   // SAME pad col 224

  // ---- zero pad column 112 of h1 (4 rows), and row 112 (block gR==0) ----
  h1b[((size_t)((4 * gR + (tid >> 6)) * 113 + 112)) * 64 + (tid & 63)] = 0;
  if (gR == 0) {
    unsigned int* z = (unsigned int*)&h1b[(size_t)112 * 113 * 64];
    for (int i = tid; i < 3616; i += 256) z[i] = 0;
  }

  // ---- per-lane weight fragments & bias ----
  half8 wf[4];
#pragma unroll
  for (int m = 0; m < 4; ++m)
    wf[m] = *(const half8*)&w1f_all[(((size_t)(e * 4 + m)) * 64 + lane) * 8];
  float4 bv[4];
#pragma unroll
  for (int m = 0; m < 4; ++m)
    bv[m] = *(const float4*)&b1[m * 16 + 4 * q];

  // ---- per-lane im2col gather offsets (k = q*8+j; k = ic*9+kh*3+kw) ----
  int off[8];
#pragma unroll
  for (int j = 0; j < 8; ++j) {
    int kk = q * 8 + j;
    if (kk < 27) {
      int ic = kk / 9;
      int r9 = kk - ic * 9;
      int kh = r9 / 3;
      int kw = r9 - kh * 3;
      off[j] = (ic * 9 + kh) * CW + kw;
    } else {
      off[j] = -1;
    }
  }

  __syncthreads();

  const int row   = 4 * gR + w;         // output row, always < 112
  const int rbase = (2 * w) * CW;       // local input row = 2w + kh

  for (int nt = 0; nt < 7; ++nt) {
    const int c = nt * 16 + n;          // output col, < 112
    const int base = rbase + 2 * c;
    unsigned int g[8];
#pragma unroll
    for (int j = 0; j < 8; ++j)
      g[j] = (off[j] >= 0) ? xs[base + off[j]] : 0u;
    union { half8 h; unsigned int u[4]; } bh;
#pragma unroll
    for (int p = 0; p < 4; ++p)
      bh.u[p] = (g[2 * p] & 0xffffu) | (g[2 * p + 1] << 16);
    f32x4 acc[4];
#pragma unroll
    for (int m = 0; m < 4; ++m) acc[m] = (f32x4){0.f, 0.f, 0.f, 0.f};
#pragma unroll
    for (int m = 0; m < 4; ++m)
      acc[m] = __builtin_amdgcn_mfma_f32_16x16x32_f16(wf[m], bh.h, acc[m], 0, 0, 0);
    // C/D: col=lane&15 (=px), row=4q+reg (oc = m*16+4q+reg)
    // store slot = q*16 + m*4 + reg  -> lane covers 32B contiguous
    size_t po = ((size_t)(row * 113 + c)) * 64 + q * 16;
    union { ushort us[16]; uint4 v4[2]; } pk;
#pragma unroll
    for (int m = 0; m < 4; ++m) {
      pk.us[m * 4 + 0] = f2h(fmaxf(acc[m][0] + bv[m].x, 0.f));
      pk.us[m * 4 + 1] = f2h(fmaxf(acc[m][1] + bv[m].y, 0.f));
      pk.us[m * 4 + 2] = f2h(fmaxf(acc[m][2] + bv[m].z, 0.f));
      pk.us[m * 4 + 3] = f2h(fmaxf(acc[m][3] + bv[m].w, 0.f));
    }
    *(uint4*)&h1b[po]     = pk.v4[0];
    *(uint4*)&h1b[po + 8] = pk.v4[1];
  }
}

// conv2 via MFMA. Block (T 0..27, b, e), 4 waves. Out rows {2T, 2T+1} (56 rows).
// Wave w: octiles {2w,2w+1} (32 oc), 7 N-tiles (8px x 2rows), all 18 kc.
// af fully preloaded to VGPRs (36 frags, issued before staging). Stage-once:
// h1 rows 4T..4T+4 in LDS (72.3KB), ONE barrier, then pure ds_read+MFMA.
// Granule swizzle: granule g of col hx stored at g^(hx&7).
__global__ __launch_bounds__(256, 2) void conv2_mfma(
    const ushort* __restrict__ h1_all,
    const ushort* __restrict__ w2frag,
    const float* __restrict__ b2_t, const float* __restrict__ b2_f,
    float* __restrict__ g)
{
  const int T = blockIdx.x;
  const int b = blockIdx.y;
  const int e = blockIdx.z;
  const int tid  = threadIdx.x;
  const int w    = tid >> 6;
  const int lane = tid & 63;
  const ushort* h1b = h1_all + (size_t)e * H1E_US + (size_t)b * H1B_US;
  const float* b2 = e ? b2_f : b2_t;

  __shared__ ushort hs[5 * 113 * 64];   // 72320 B

  const int q   = lane >> 4;
  const int n   = lane & 15;
  const int pxl = lane & 7;
  const int rl  = (lane >> 3) & 1;

  // ---- preload ALL af fragments (2 mt x 18 kc x 16B = 144 VGPR) ----
  half8 afr[2][18];
#pragma unroll
  for (int mt = 0; mt < 2; ++mt)
#pragma unroll
    for (int kc = 0; kc < 18; ++kc)
      afr[mt][kc] = *(const half8*)
          &w2frag[((size_t)((e * 8 + 2 * w + mt) * 18 + kc)) * 512 + lane * 8];

  // ---- stage 5 h1 rows (4520 granules of 16B), swizzled, reg-staged ----
#pragma unroll
  for (int half = 0; half < 2; ++half) {
    bf16x8 tmp[9];
    int dst[9];
    bool ok[9];
#pragma unroll
    for (int k = 0; k < 9; ++k) {
      int s = tid + (half * 9 + k) * 256;
      ok[k] = (s < 4520);
      int r = s / 904;
      int rem = s - 904 * r;
      int hx = rem >> 3, gq = rem & 7;
      if (ok[k])
        tmp[k] = *(const bf16x8*)&h1b[((size_t)((4 * T + r) * 113 + hx)) * 64 + 8 * gq];
      dst[k] = (r * 113 + hx) * 64 + 8 * (gq ^ (hx & 7));
    }
#pragma unroll
    for (int k = 0; k < 9; ++k)
      if (ok[k]) *(bf16x8*)&hs[dst[k]] = tmp[k];
  }
  __syncthreads();

  f32x4 acc[2][7];
#pragma unroll
  for (int mt = 0; mt < 2; ++mt)
#pragma unroll
    for (int nt = 0; nt < 7; ++nt) acc[mt][nt] = (f32x4){0.f, 0.f, 0.f, 0.f};

#pragma unroll
  for (int kh = 0; kh < 3; ++kh) {
    const int rbase = (kh + 2 * rl) * 113 * 64;   // local h1 row = kh+2*rl
#pragma unroll
    for (int kw = 0; kw < 3; ++kw) {
#pragma unroll
      for (int icc = 0; icc < 2; ++icc) {
        const int kc = kh * 6 + kw * 2 + icc;
        const int gsw = 8 * ((icc * 4 + q) ^ ((2 * pxl + kw) & 7));
        half8 bf[7];
#pragma unroll
        for (int nt = 0; nt < 7; ++nt) {
          int hx = 2 * (8 * nt + pxl) + kw;
          bf[nt] = *(const half8*)&hs[rbase + hx * 64 + gsw];
        }
#pragma unroll
        for (int mt = 0; mt < 2; ++mt) {
#pragma unroll
          for (int nt = 0; nt < 7; ++nt)
            acc[mt][nt] = __builtin_amdgcn_mfma_f32_16x16x32_f16(
                afr[mt][kc], bf[nt], acc[mt][nt], 0, 0, 0);
        }
      }
    }
  }

#pragma unroll
  for (int mt = 0; mt < 2; ++mt) {
#pragma unroll
    for (int reg = 0; reg < 4; ++reg) {
      const int oc = 32 * w + 16 * mt + 4 * q + reg;
      const float bias = b2[oc];
      float s = 0.f;
#pragma unroll
      for (int nt = 0; nt < 7; ++nt) s += fmaxf(acc[mt][nt][reg] + bias, 0.f);
      s += __shfl_xor(s, 1);
      s += __shfl_xor(s, 2);
      s += __shfl_xor(s, 4);
      s += __shfl_xor(s, 8);
      if (n == 0) atomicAdd(&g[((size_t)e * 64 + b) * 128 + oc], s);
    }
  }
}

__global__ __launch_bounds__(64) void finale(
    const float* __restrict__ g,
    const float* __restrict__ t_wf, const float* __restrict__ t_bf,
    const float* __restrict__ f_wf, const float* __restrict__ f_bf,
    float* __restrict__ out)
{
  const int b = threadIdx.x;
  const float inv = 1.0f / 3136.0f;
  const float* gt = g + b * 128;
  const float* gf = g + (64 + b) * 128;
  float lt0 = t_bf[0], lt1 = t_bf[1];
  float lf0 = f_bf[0], lf1 = f_bf[1];
  for (int k = 0; k < 128; ++k) {
    float vt = gt[k] * inv;
    float vf = gf[k] * inv;
    lt0 = fmaf(vt, t_wf[2 * k],     lt0);
    lt1 = fmaf(vt, t_wf[2 * k + 1], lt1);
    lf0 = fmaf(vf, f_wf[2 * k],     lf0);
    lf1 = fmaf(vf, f_wf[2 * k + 1], lf1);
  }
  float m  = fmaxf(lt0, lt1);
  float e0 = expf(lt0 - m), e1 = expf(lt1 - m);
  float conf = fmaxf(e0, e1) / (e0 + e1);
  bool use2 = (conf <= 0.9f);
  out[2 * b]     = use2 ? 0.7f * lt0 + 0.3f * lf0 : lt0;
  out[2 * b + 1] = use2 ? 0.7f * lt1 + 0.3f * lf1 : lt1;
  unsigned long long mask = __ballot(use2);
  if (b == 0) out[128] = (float)__popcll(mask) * (1.0f / 64.0f);
}

// ---------------- fallback (ws too small): round-1 fused fp32 ----------------
__global__ __launch_bounds__(256) void transpose_w2(
    const float* __restrict__ w2_t, const float* __restrict__ w2_f,
    float* __restrict__ w2t) {
  int idx = blockIdx.x * 256 + threadIdx.x;
  int e = idx / 73728;
  int r = idx - e * 73728;
  int k = r >> 7, oc = r & 127;
  const float* src = e ? w2_f : w2_t;
  w2t[idx] = src[oc * 576 + k];
}

__global__ __launch_bounds__(256, 3) void fused_expert(
    const float* __restrict__ x,
    const float* __restrict__ w1_t, const float* __restrict__ b1_t,
    const float* __restrict__ b2_t,
    const float* __restrict__ w1_f, const float* __restrict__ b1_f,
    const float* __restrict__ b2_f,
    const float* __restrict__ w2t_all, float* __restrict__ g)
{
  const int tile = blockIdx.x, b = blockIdx.y, e = blockIdx.z;
  const int ty = tile >> 1, tx = tile & 1;
  const float* w1  = e ? w1_f : w1_t;
  const float* b1  = e ? b1_f : b1_t;
  const float* b2  = e ? b2_f : b2_t;
  const float* w2t = w2t_all + e * 73728;
  __shared__ float x_s[3 * 19 * 116];
  __shared__ float h1_s[8 * 9 * 58];
  __shared__ float w1_s[1728];
  const int tid = threadIdx.x;
  {
    const float* xb = x + (size_t)b * 150528;
    const int xr0 = ty * 16, xc0 = tx * 112;
    for (int idx = tid; idx < 3 * 19 * 116; idx += 256) {
      int ic = idx / (19 * 116);
      int rem = idx - ic * (19 * 116);
      int r = rem / 116, cc = rem - r * 116;
      int xr = xr0 + r, xc = xc0 + cc;
      float v = 0.f;
      if (xr < 224 && xc < 224 && cc < 115) v = xb[(ic * 224 + xr) * 224 + xc];
      x_s[idx] = v;
    }
    for (int idx = tid; idx < 1728; idx += 256) w1_s[idx] = w1[idx];
  }
  const int ocg = tid >> 4, posg = tid & 15;
  int pbase[7];
#pragma unroll
  for (int j = 0; j < 7; ++j) {
    int p = posg + 16 * j, py = p / 28, px = p - py * 28;
    pbase[j] = py * 2 * 58 + px * 2;
  }
  float acc[7][8];
#pragma unroll
  for (int j = 0; j < 7; ++j)
#pragma unroll
    for (int i = 0; i < 8; ++i) acc[j][i] = 0.f;
  const int hc_l = tid >> 5, l32 = tid & 31;
  for (int c = 0; c < 8; ++c) {
    __syncthreads();
    {
      const int hc = c * 8 + hc_l;
      const float bias = b1[hc];
      float wr[27];
#pragma unroll
      for (int qq = 0; qq < 27; ++qq) wr[qq] = w1_s[hc * 27 + qq];
      for (int p = l32; p < 513; p += 32) {
        int hy = p / 57, hx = p - hy * 57;
        float a = bias;
#pragma unroll
        for (int ic = 0; ic < 3; ++ic)
#pragma unroll
          for (int kh = 0; kh < 3; ++kh) {
            const float* row = &x_s[ic * (19 * 116) + (2 * hy + kh) * 116 + 2 * hx];
            a = fmaf(row[0], wr[ic * 9 + kh * 3 + 0], a);
            a = fmaf(row[1], wr[ic * 9 + kh * 3 + 1], a);
            a = fmaf(row[2], wr[ic * 9 + kh * 3 + 2], a);
          }
        float v = fmaxf(a, 0.f);
        int hy_g = ty * 8 + hy, hx_g = tx * 56 + hx;
        if (hy_g >= 112 || hx_g >= 112) v = 0.f;
        h1_s[hc_l * 522 + hy * 58 + hx] = v;
      }
    }
    __syncthreads();
    for (int ic_l = 0; ic_l < 8; ++ic_l) {
#pragma unroll
      for (int kh = 0; kh < 3; ++kh)
#pragma unroll
        for (int kw = 0; kw < 3; ++kw) {
          const int k = (c * 8 + ic_l) * 9 + kh * 3 + kw;
          const float4 wA = *(const float4*)(w2t + k * 128 + ocg * 8);
          const float4 wB = *(const float4*)(w2t + k * 128 + ocg * 8 + 4);
          const float* hp = &h1_s[ic_l * 522 + kh * 58 + kw];
#pragma unroll
          for (int j = 0; j < 7; ++j) {
            float h = hp[pbase[j]];
            acc[j][0] = fmaf(wA.x, h, acc[j][0]);
            acc[j][1] = fmaf(wA.y, h, acc[j][1]);
            acc[j][2] = fmaf(wA.z, h, acc[j][2]);
            acc[j][3] = fmaf(wA.w, h, acc[j][3]);
            acc[j][4] = fmaf(wB.x, h, acc[j][4]);
            acc[j][5] = fmaf(wB.y, h, acc[j][5]);
            acc[j][6] = fmaf(wB.z, h, acc[j][6]);
            acc[j][7] = fmaf(wB.w, h, acc[j][7]);
          }
        }
    }
  }
  __syncthreads();
  float* red = x_s;
#pragma unroll
  for (int i = 0; i < 8; ++i) {
    float bb = b2[ocg * 8 + i];
    float t = 0.f;
#pragma unroll
    for (int j = 0; j < 7; ++j) t += fmaxf(acc[j][i] + bb, 0.f);
    red[posg * 129 + ocg * 8 + i] = t;
  }
  __syncthreads();
  if (tid < 128) {
    float t = 0.f;
#pragma unroll
    for (int pg = 0; pg < 16; ++pg) t += red[pg * 129 + tid];
    atomicAdd(&g[(e * 64 + b) * 128 + tid], t);
  }
}

extern "C" void kernel_launch(void* const* d_in, const int* in_sizes, int n_in,
                              void* d_out, int out_size, void* d_ws, size_t ws_size,
                              hipStream_t stream) {
  const float* x    = (const float*)d_in[0];
  const float* t_w1 = (const float*)d_in[1];
  const float* t_b1 = (const float*)d_in[2];
  const float* t_w2 = (const float*)d_in[3];
  const float* t_b2 = (const float*)d_in[4];
  const float* t_wf = (const float*)d_in[5];
  const float* t_bf = (const float*)d_in[6];
  const float* f_w1 = (const float*)d_in[7];
  const float* f_b1 = (const float*)d_in[8];
  const float* f_w2 = (const float*)d_in[9];
  const float* f_b2 = (const float*)d_in[10];
  const float* f_wf = (const float*)d_in[11];
  const float* f_bf = (const float*)d_in[12];
  float* out = (float*)d_out;
  char* ws = (char*)d_ws;

  if (ws_size >= WS_NEED) {
    float*  gbuf   = (float*)(ws + G_OFF);
    ushort* h1     = (ushort*)(ws + H1_OFF);
    ushort* w2frag = (ushort*)(ws + W2B_OFF);
    ushort* w1f    = (ushort*)(ws + W1F_OFF);
    hipMemsetAsync(gbuf, 0, 2 * 64 * 128 * sizeof(float), stream);
    prep_new<<<592, 256, 0, stream>>>(t_w2, f_w2, t_w1, f_w1, ws);
    conv1_mfma<<<dim3(28, 64, 2), 256, 0, stream>>>(x, w1f, t_b1, f_b1, h1);
    conv2_mfma<<<dim3(28, 64, 2), 256, 0, stream>>>(h1, w2frag, t_b2, f_b2, gbuf);
    finale<<<1, 64, 0, stream>>>(gbuf, t_wf, t_bf, f_wf, f_bf, out);
  } else {
    float* w2t = (float*)ws;
    float* g2  = (float*)(ws + 589824);
    hipMemsetAsync(g2, 0, 2 * 64 * 128 * sizeof(float), stream);
    transpose_w2<<<576, 256, 0, stream>>>(t_w2, f_w2, w2t);
    fused_expert<<<dim3(28, 64, 2), 256, 0, stream>>>(
        x, t_w1, t_b1, t_b2, f_w1, f_b1, f_b2, w2t, g2);
    finale<<<1, 64, 0, stream>>>(g2, t_wf, t_bf, f_wf, f_bf, out);
  }
}